// Round 1
// baseline (907.168 us; speedup 1.0000x reference)
//
#include <hip/hip_runtime.h>

#define D 128

// ---------------- edge dtype handling ----------------
// Reference declares int64 edge_index, but JAX default (x64 disabled) yields
// int32. Detect on device: if the first 4096 odd 32-bit words are all zero,
// the buffer is little-endian int64 (values < 2^17). Write flag to ws.
__global__ void detect64_k(const int* __restrict__ raw, int* __restrict__ flag) {
    __shared__ int bad;
    if (threadIdx.x == 0) bad = 0;
    __syncthreads();
    for (int i = threadIdx.x; i < 4096; i += 256)
        if (raw[2 * i + 1] != 0) bad = 1;   // benign race, all write 1
    __syncthreads();
    if (threadIdx.x == 0) *flag = bad ? 0 : 1;
}

// Convert edge buffer to contiguous int32 [src(E), dst(E)]
__global__ void cvt_k(const int* __restrict__ raw, const int* __restrict__ flag,
                      int* __restrict__ out, int n2) {
    bool is64 = (*flag != 0);
    for (int i = blockIdx.x * blockDim.x + threadIdx.x; i < n2;
         i += gridDim.x * blockDim.x)
        out[i] = is64 ? raw[2 * i] : raw[i];
}

// ---------------- degree / norm ----------------
__global__ void hist_k(const int* __restrict__ dst, int* __restrict__ cnt, int E) {
    for (int i = blockIdx.x * blockDim.x + threadIdx.x; i < E;
         i += gridDim.x * blockDim.x)
        atomicAdd(&cnt[dst[i]], 1);
}

__global__ void dinv_k(const int* __restrict__ cnt, float* __restrict__ dinv, int n) {
    int i = blockIdx.x * blockDim.x + threadIdx.x;
    if (i < n) dinv[i] = rsqrtf((float)cnt[i] + 1.0f);   // +1 = self-loop
}

// ---------------- CSR build: block scan (1024 elems/block) ----------------
__global__ void scan1_k(const int* __restrict__ cnt, int* __restrict__ rp,
                        int* __restrict__ part, int n) {
    __shared__ int s[256];
    int t = threadIdx.x;
    int base = blockIdx.x * 1024 + t * 4;
    int v0 = 0, v1 = 0, v2 = 0, v3 = 0;
    if (base + 0 < n) v0 = cnt[base + 0];
    if (base + 1 < n) v1 = cnt[base + 1];
    if (base + 2 < n) v2 = cnt[base + 2];
    if (base + 3 < n) v3 = cnt[base + 3];
    int sum = v0 + v1 + v2 + v3;
    s[t] = sum;
    __syncthreads();
    for (int off = 1; off < 256; off <<= 1) {
        int xv = 0;
        if (t >= off) xv = s[t - off];
        __syncthreads();
        s[t] += xv;
        __syncthreads();
    }
    int run = s[t] - sum;   // exclusive prefix for this thread's 4 elems
    if (base + 0 < n) rp[base + 0] = run; run += v0;
    if (base + 1 < n) rp[base + 1] = run; run += v1;
    if (base + 2 < n) rp[base + 2] = run; run += v2;
    if (base + 3 < n) rp[base + 3] = run;
    if (t == 255) part[blockIdx.x] = s[255];
}

__global__ void scan2_k(int* __restrict__ part, int nb) {
    if (threadIdx.x == 0 && blockIdx.x == 0) {
        int run = 0;
        for (int i = 0; i < nb; i++) { int v = part[i]; part[i] = run; run += v; }
    }
}

__global__ void scan3_k(int* __restrict__ rp, int* __restrict__ cursor,
                        const int* __restrict__ part, int n, int E) {
    int i = blockIdx.x * blockDim.x + threadIdx.x;
    if (i < n) {
        int v = rp[i] + part[i >> 10];
        rp[i] = v;
        cursor[i] = v;
    }
    if (i == 0) rp[n] = E;
}

__global__ void build_k(const int* __restrict__ src, const int* __restrict__ dst,
                        int* __restrict__ cursor, int* __restrict__ csr, int E) {
    for (int i = blockIdx.x * blockDim.x + threadIdx.x; i < E;
         i += gridDim.x * blockDim.x) {
        int pos = atomicAdd(&cursor[dst[i]], 1);
        csr[pos] = src[i];
    }
}

// ---------------- GEMM: H = preop(A) @ W  (M x 128 @ 128 x 128, f32) -------
// BM=64, BN=128, BK=64, 256 threads, per-thread 4x8 microtile.
template <int PRE>   // 0: identity, 1: relu on A-load
__global__ __launch_bounds__(256) void gemm_k(const float* __restrict__ A,
                                              const float* __restrict__ W,
                                              float* __restrict__ H, int M) {
    __shared__ float As[64][65];    // [k][m], +1 pad
    __shared__ float Ws[64][128];   // [k][n]
    int t = threadIdx.x;
    int row0 = blockIdx.x * 64;
    int trow = t >> 4;   // 0..15 -> rows trow*4..+3
    int tcol = t & 15;   // 0..15 -> cols tcol*8..+7
    float acc[4][8];
#pragma unroll
    for (int i = 0; i < 4; i++)
#pragma unroll
        for (int j = 0; j < 8; j++) acc[i][j] = 0.0f;

    for (int k0 = 0; k0 < 128; k0 += 64) {
        // A tile load (transposed into LDS), rows (t>>4)+16i, cols (t&15)*4
        {
            int c = (t & 15) * 4;
#pragma unroll
            for (int i = 0; i < 4; i++) {
                int r = (t >> 4) + 16 * i;
                int row = row0 + r;
                if (row >= M) row = M - 1;   // clamp; stores guarded
                float4 v = *(const float4*)(A + (size_t)row * D + k0 + c);
                if (PRE) {
                    v.x = fmaxf(v.x, 0.0f); v.y = fmaxf(v.y, 0.0f);
                    v.z = fmaxf(v.z, 0.0f); v.w = fmaxf(v.w, 0.0f);
                }
                As[c + 0][r] = v.x; As[c + 1][r] = v.y;
                As[c + 2][r] = v.z; As[c + 3][r] = v.w;
            }
            // W tile: rows (t>>5)+8i, cols (t&31)*4
            int c2 = (t & 31) * 4;
#pragma unroll
            for (int i = 0; i < 8; i++) {
                int k = (t >> 5) + 8 * i;
                *(float4*)&Ws[k][c2] = *(const float4*)(W + (size_t)(k0 + k) * D + c2);
            }
        }
        __syncthreads();
#pragma unroll 8
        for (int kk = 0; kk < 64; ++kk) {
            float4 a  = *(const float4*)&As[kk][trow * 4];
            float4 w0 = *(const float4*)&Ws[kk][tcol * 8];
            float4 w1 = *(const float4*)&Ws[kk][tcol * 8 + 4];
            float av[4] = {a.x, a.y, a.z, a.w};
            float wv[8] = {w0.x, w0.y, w0.z, w0.w, w1.x, w1.y, w1.z, w1.w};
#pragma unroll
            for (int i = 0; i < 4; i++)
#pragma unroll
                for (int j = 0; j < 8; j++)
                    acc[i][j] = fmaf(av[i], wv[j], acc[i][j]);
        }
        __syncthreads();
    }
#pragma unroll
    for (int i = 0; i < 4; i++) {
        int row = row0 + trow * 4 + i;
        if (row < M) {
            float4 o0 = {acc[i][0], acc[i][1], acc[i][2], acc[i][3]};
            float4 o1 = {acc[i][4], acc[i][5], acc[i][6], acc[i][7]};
            *(float4*)(H + (size_t)row * D + tcol * 8)     = o0;
            *(float4*)(H + (size_t)row * D + tcol * 8 + 4) = o1;
        }
    }
}

// ---------------- CSR aggregation: out[n] = b + dinv[n]^2 h[n] + sum --------
// one wave per node; 64 lanes x float2 = 128 cols; 2-edge unroll.
__global__ __launch_bounds__(256) void agg_k(const float* __restrict__ h,
                                             const float* __restrict__ dinv,
                                             const int* __restrict__ rp,
                                             const int* __restrict__ csr,
                                             const float* __restrict__ bias,
                                             float* __restrict__ out, int n) {
    int node = (blockIdx.x << 2) + (threadIdx.x >> 6);
    int lane = threadIdx.x & 63;
    if (node >= n) return;
    const float2* h2 = (const float2*)h;
    float2 b2 = ((const float2*)bias)[lane];
    float dn = dinv[node];
    float2 hv = h2[(size_t)node * 64 + lane];
    float sl = dn * dn;   // self-loop norm
    float accx = b2.x + sl * hv.x;
    float accy = b2.y + sl * hv.y;
    int e = rp[node], e1 = rp[node + 1];
    for (; e + 1 < e1; e += 2) {
        int s0 = csr[e], s1 = csr[e + 1];
        float w0 = dinv[s0] * dn, w1 = dinv[s1] * dn;
        float2 v0 = h2[(size_t)s0 * 64 + lane];
        float2 v1 = h2[(size_t)s1 * 64 + lane];
        accx += w0 * v0.x + w1 * v1.x;
        accy += w0 * v0.y + w1 * v1.y;
    }
    if (e < e1) {
        int s0 = csr[e];
        float w0 = dinv[s0] * dn;
        float2 v0 = h2[(size_t)s0 * 64 + lane];
        accx += w0 * v0.x;
        accy += w0 * v0.y;
    }
    float2 o; o.x = accx; o.y = accy;
    ((float2*)out)[(size_t)node * 64 + lane] = o;
}

extern "C" void kernel_launch(void* const* d_in, const int* in_sizes, int n_in,
                              void* d_out, int out_size, void* d_ws, size_t ws_size,
                              hipStream_t stream) {
    const float* x  = (const float*)d_in[0];
    const int* eraw = (const int*)d_in[1];
    const float* W1 = (const float*)d_in[2];
    const float* b1 = (const float*)d_in[3];
    const float* W2 = (const float*)d_in[4];
    const float* b2 = (const float*)d_in[5];
    const float* W3 = (const float*)d_in[6];
    const float* b3 = (const float*)d_in[7];
    int N = in_sizes[0] / D;
    int E = in_sizes[1] / 2;
    float* out = (float*)d_out;

    // workspace carve-up (~72 MB)
    char* w = (char*)d_ws;
    float* h    = (float*)w; w += (size_t)N * D * 4;
    int* s32    = (int*)w;   w += (size_t)2 * E * 4;   // [src(E), dst(E)]
    int* csr    = (int*)w;   w += (size_t)E * 4;
    int* cnt    = (int*)w;   w += (size_t)N * 4;
    float* dinv = (float*)w; w += (size_t)N * 4;
    int* rp     = (int*)w;   w += (size_t)(N + 1) * 4;
    int* cursor = (int*)w;   w += (size_t)N * 4;
    int* part   = (int*)w;   w += 1024 * 4;
    int* flag   = (int*)w;   w += 16;
    int* src32 = s32;
    int* dst32 = s32 + E;

    // graph structure (recomputed every call; inputs restored by harness)
    detect64_k<<<1, 256, 0, stream>>>(eraw, flag);
    cvt_k<<<2048, 256, 0, stream>>>(eraw, flag, s32, 2 * E);
    hipMemsetAsync(cnt, 0, (size_t)N * 4, stream);
    hist_k<<<2048, 256, 0, stream>>>(dst32, cnt, E);
    dinv_k<<<(N + 255) / 256, 256, 0, stream>>>(cnt, dinv, N);
    int nb = (N + 1023) / 1024;
    scan1_k<<<nb, 256, 0, stream>>>(cnt, rp, part, N);
    scan2_k<<<1, 64, 0, stream>>>(part, nb);
    scan3_k<<<(N + 255) / 256, 256, 0, stream>>>(rp, cursor, part, N, E);
    build_k<<<2048, 256, 0, stream>>>(src32, dst32, cursor, csr, E);

    int gb = (N + 63) / 64;
    int ab = (N + 3) / 4;
    // layer 1
    gemm_k<0><<<gb, 256, 0, stream>>>(x, W1, h, N);
    agg_k<<<ab, 256, 0, stream>>>(h, dinv, rp, csr, b1, out, N);
    // layer 2 (relu fused into A-load)
    gemm_k<1><<<gb, 256, 0, stream>>>(out, W2, h, N);
    agg_k<<<ab, 256, 0, stream>>>(h, dinv, rp, csr, b2, out, N);
    // layer 3 (no relu after)
    gemm_k<1><<<gb, 256, 0, stream>>>(out, W3, h, N);
    agg_k<<<ab, 256, 0, stream>>>(h, dinv, rp, csr, b3, out, N);
}

// Round 7
// 805.847 us; speedup vs baseline: 1.1257x; 1.1257x over previous
//
#include <hip/hip_runtime.h>

#define D 128

// ---------------- edge dtype handling ----------------
// Reference declares int64 edge_index, but JAX default (x64 disabled) yields
// int32. Detect on device: if the first 4096 odd 32-bit words are all zero,
// the buffer is little-endian int64 (values < 2^17).
__global__ void detect64_k(const int* __restrict__ raw, int* __restrict__ flag) {
    __shared__ int bad;
    if (threadIdx.x == 0) bad = 0;
    __syncthreads();
    for (int i = threadIdx.x; i < 4096; i += 256)
        if (raw[2 * i + 1] != 0) bad = 1;   // benign race, all write 1
    __syncthreads();
    if (threadIdx.x == 0) *flag = bad ? 0 : 1;
}

// ---------------- degree ----------------
// reads dst directly from raw edge buffer (handles int32/int64 layouts)
__global__ void hist_k(const int* __restrict__ raw, const int* __restrict__ flag,
                       int* __restrict__ cnt, int E) {
    bool is64 = (*flag != 0);
    for (int i = blockIdx.x * blockDim.x + threadIdx.x; i < E;
         i += gridDim.x * blockDim.x) {
        int d = is64 ? raw[2 * (E + i)] : raw[E + i];
        atomicAdd(&cnt[d], 1);
    }
}

__global__ void dinv_k(const int* __restrict__ cnt, float* __restrict__ dinv, int n) {
    int i = blockIdx.x * blockDim.x + threadIdx.x;
    if (i < n) dinv[i] = rsqrtf((float)cnt[i] + 1.0f);   // +1 = self-loop
}

// ---------------- CSR build: block scan (1024 elems/block) ----------------
__global__ void scan1_k(const int* __restrict__ cnt, int* __restrict__ rp,
                        int* __restrict__ part, int n) {
    __shared__ int s[256];
    int t = threadIdx.x;
    int base = blockIdx.x * 1024 + t * 4;
    int v0 = 0, v1 = 0, v2 = 0, v3 = 0;
    if (base + 0 < n) v0 = cnt[base + 0];
    if (base + 1 < n) v1 = cnt[base + 1];
    if (base + 2 < n) v2 = cnt[base + 2];
    if (base + 3 < n) v3 = cnt[base + 3];
    int sum = v0 + v1 + v2 + v3;
    s[t] = sum;
    __syncthreads();
    for (int off = 1; off < 256; off <<= 1) {
        int xv = 0;
        if (t >= off) xv = s[t - off];
        __syncthreads();
        s[t] += xv;
        __syncthreads();
    }
    int run = s[t] - sum;   // exclusive prefix for this thread's 4 elems
    if (base + 0 < n) rp[base + 0] = run; run += v0;
    if (base + 1 < n) rp[base + 1] = run; run += v1;
    if (base + 2 < n) rp[base + 2] = run; run += v2;
    if (base + 3 < n) rp[base + 3] = run;
    if (t == 255) part[blockIdx.x] = s[255];
}

__global__ void scan2_k(int* __restrict__ part, int nb) {
    if (threadIdx.x == 0 && blockIdx.x == 0) {
        int run = 0;
        for (int i = 0; i < nb; i++) { int v = part[i]; part[i] = run; run += v; }
    }
}

__global__ void scan3_k(int* __restrict__ rp, int* __restrict__ cursor,
                        const int* __restrict__ part, int n, int E) {
    int i = blockIdx.x * blockDim.x + threadIdx.x;
    if (i < n) {
        int v = rp[i] + part[i >> 10];
        rp[i] = v;
        cursor[i] = v;
    }
    if (i == 0) rp[n] = E;
}

// CSR entry = {src index, norm weight dinv[src]*dinv[dst]} packed as int2
__global__ void build_k(const int* __restrict__ raw, const int* __restrict__ flag,
                        const float* __restrict__ dinv,
                        int* __restrict__ cursor, int2* __restrict__ csr, int E) {
    bool is64 = (*flag != 0);
    for (int i = blockIdx.x * blockDim.x + threadIdx.x; i < E;
         i += gridDim.x * blockDim.x) {
        int s = is64 ? raw[2 * i] : raw[i];
        int d = is64 ? raw[2 * (E + i)] : raw[E + i];
        int pos = atomicAdd(&cursor[d], 1);
        float w = dinv[s] * dinv[d];
        csr[pos] = make_int2(s, __float_as_int(w));
    }
}

// ---------------- GEMM: H = preop(A) @ W  (M x 128 @ 128 x 128, f32) -------
// BM=128, BN=128, BK=64, 256 threads, per-thread 8x8 microtile.
template <int PRE>   // 0: identity, 1: relu on A-load
__global__ __launch_bounds__(256) void gemm_k(const float* __restrict__ A,
                                              const float* __restrict__ W,
                                              float* __restrict__ H, int M) {
    __shared__ float As[64][129];   // [k][m], +1 pad
    __shared__ float Ws[64][128];   // [k][n]
    int t = threadIdx.x;
    int row0 = blockIdx.x * 128;
    int trow = t >> 4;   // 0..15 -> rows trow*8..+7
    int tcol = t & 15;   // 0..15 -> cols tcol*8..+7
    float acc[8][8];
#pragma unroll
    for (int i = 0; i < 8; i++)
#pragma unroll
        for (int j = 0; j < 8; j++) acc[i][j] = 0.0f;

    for (int k0 = 0; k0 < 128; k0 += 64) {
        // A tile: 128 rows x 64 cols, transposed into LDS.
        // thread t: rows (t>>4)+16i (i=0..7), cols (t&15)*4
        {
            int c = (t & 15) * 4;
#pragma unroll
            for (int i = 0; i < 8; i++) {
                int r = (t >> 4) + 16 * i;
                int row = row0 + r;
                if (row >= M) row = M - 1;   // clamp; stores guarded
                float4 v = *(const float4*)(A + (size_t)row * D + k0 + c);
                if (PRE) {
                    v.x = fmaxf(v.x, 0.0f); v.y = fmaxf(v.y, 0.0f);
                    v.z = fmaxf(v.z, 0.0f); v.w = fmaxf(v.w, 0.0f);
                }
                As[c + 0][r] = v.x; As[c + 1][r] = v.y;
                As[c + 2][r] = v.z; As[c + 3][r] = v.w;
            }
            // W tile: 64 rows x 128 cols: rows (t>>5)+8i, cols (t&31)*4
            int c2 = (t & 31) * 4;
#pragma unroll
            for (int i = 0; i < 8; i++) {
                int k = (t >> 5) + 8 * i;
                *(float4*)&Ws[k][c2] = *(const float4*)(W + (size_t)(k0 + k) * D + c2);
            }
        }
        __syncthreads();
#pragma unroll 4
        for (int kk = 0; kk < 64; ++kk) {
            float4 a0 = *(const float4*)&As[kk][trow * 8];
            float4 a1 = *(const float4*)&As[kk][trow * 8 + 4];
            float4 w0 = *(const float4*)&Ws[kk][tcol * 8];
            float4 w1 = *(const float4*)&Ws[kk][tcol * 8 + 4];
            float av[8] = {a0.x, a0.y, a0.z, a0.w, a1.x, a1.y, a1.z, a1.w};
            float wv[8] = {w0.x, w0.y, w0.z, w0.w, w1.x, w1.y, w1.z, w1.w};
#pragma unroll
            for (int i = 0; i < 8; i++)
#pragma unroll
                for (int j = 0; j < 8; j++)
                    acc[i][j] = fmaf(av[i], wv[j], acc[i][j]);
        }
        __syncthreads();
    }
#pragma unroll
    for (int i = 0; i < 8; i++) {
        int row = row0 + trow * 8 + i;
        if (row < M) {
            float4 o0 = {acc[i][0], acc[i][1], acc[i][2], acc[i][3]};
            float4 o1 = {acc[i][4], acc[i][5], acc[i][6], acc[i][7]};
            *(float4*)(H + (size_t)row * D + tcol * 8)     = o0;
            *(float4*)(H + (size_t)row * D + tcol * 8 + 4) = o1;
        }
    }
}

// ---------------- CSR aggregation: out[n] = b + dinv[n]^2 h[n] + sum --------
// one wave per node; 64 lanes x float2 = 128 cols; 4-edge unroll, weights
// pre-folded into csr entries (no dependent dinv gather).
__global__ __launch_bounds__(256) void agg_k(const float* __restrict__ h,
                                             const float* __restrict__ dinv,
                                             const int* __restrict__ rp,
                                             const int2* __restrict__ csr,
                                             const float* __restrict__ bias,
                                             float* __restrict__ out, int n) {
    int node = (blockIdx.x << 2) + (threadIdx.x >> 6);
    int lane = threadIdx.x & 63;
    if (node >= n) return;
    const float2* h2 = (const float2*)h;
    float2 b2 = ((const float2*)bias)[lane];
    float dn = dinv[node];
    float2 hv = h2[(size_t)node * 64 + lane];
    float sl = dn * dn;   // self-loop norm
    float accx = b2.x + sl * hv.x;
    float accy = b2.y + sl * hv.y;
    int e = rp[node], e1 = rp[node + 1];
    for (; e + 4 <= e1; e += 4) {
        int2 p0 = csr[e], p1 = csr[e + 1], p2 = csr[e + 2], p3 = csr[e + 3];
        float2 v0 = h2[(size_t)p0.x * 64 + lane];
        float2 v1 = h2[(size_t)p1.x * 64 + lane];
        float2 v2 = h2[(size_t)p2.x * 64 + lane];
        float2 v3 = h2[(size_t)p3.x * 64 + lane];
        float w0 = __int_as_float(p0.y), w1 = __int_as_float(p1.y);
        float w2 = __int_as_float(p2.y), w3 = __int_as_float(p3.y);
        accx += w0 * v0.x + w1 * v1.x + w2 * v2.x + w3 * v3.x;
        accy += w0 * v0.y + w1 * v1.y + w2 * v2.y + w3 * v3.y;
    }
    for (; e < e1; ++e) {
        int2 p0 = csr[e];
        float w0 = __int_as_float(p0.y);
        float2 v0 = h2[(size_t)p0.x * 64 + lane];
        accx += w0 * v0.x;
        accy += w0 * v0.y;
    }
    float2 o; o.x = accx; o.y = accy;
    ((float2*)out)[(size_t)node * 64 + lane] = o;
}

extern "C" void kernel_launch(void* const* d_in, const int* in_sizes, int n_in,
                              void* d_out, int out_size, void* d_ws, size_t ws_size,
                              hipStream_t stream) {
    const float* x  = (const float*)d_in[0];
    const int* eraw = (const int*)d_in[1];
    const float* W1 = (const float*)d_in[2];
    const float* b1 = (const float*)d_in[3];
    const float* W2 = (const float*)d_in[4];
    const float* b2 = (const float*)d_in[5];
    const float* W3 = (const float*)d_in[6];
    const float* b3 = (const float*)d_in[7];
    int N = in_sizes[0] / D;
    int E = in_sizes[1] / 2;
    float* out = (float*)d_out;

    // workspace carve-up (~66 MB)
    char* w = (char*)d_ws;
    float* h    = (float*)w; w += (size_t)N * D * 4;
    int2* csr   = (int2*)w;  w += (size_t)E * 8;
    int* cnt    = (int*)w;   w += (size_t)N * 4;
    float* dinv = (float*)w; w += (size_t)N * 4;
    int* rp     = (int*)w;   w += (size_t)(N + 1) * 4;
    int* cursor = (int*)w;   w += (size_t)N * 4;
    int* part   = (int*)w;   w += 1024 * 4;
    int* flag   = (int*)w;   w += 16;

    // graph structure (recomputed every call; inputs restored by harness)
    detect64_k<<<1, 256, 0, stream>>>(eraw, flag);
    hipMemsetAsync(cnt, 0, (size_t)N * 4, stream);
    hist_k<<<2048, 256, 0, stream>>>(eraw, flag, cnt, E);
    dinv_k<<<(N + 255) / 256, 256, 0, stream>>>(cnt, dinv, N);
    int nb = (N + 1023) / 1024;
    scan1_k<<<nb, 256, 0, stream>>>(cnt, rp, part, N);
    scan2_k<<<1, 64, 0, stream>>>(part, nb);
    scan3_k<<<(N + 255) / 256, 256, 0, stream>>>(rp, cursor, part, N, E);
    build_k<<<2048, 256, 0, stream>>>(eraw, flag, dinv, cursor, csr, E);

    int gb = (N + 127) / 128;
    int ab = (N + 3) / 4;
    // layer 1
    gemm_k<0><<<gb, 256, 0, stream>>>(x, W1, h, N);
    agg_k<<<ab, 256, 0, stream>>>(h, dinv, rp, csr, b1, out, N);
    // layer 2 (relu fused into A-load)
    gemm_k<1><<<gb, 256, 0, stream>>>(out, W2, h, N);
    agg_k<<<ab, 256, 0, stream>>>(h, dinv, rp, csr, b2, out, N);
    // layer 3 (no relu after)
    gemm_k<1><<<gb, 256, 0, stream>>>(out, W3, h, N);
    agg_k<<<ab, 256, 0, stream>>>(h, dinv, rp, csr, b3, out, N);
}

// Round 9
// 737.299 us; speedup vs baseline: 1.2304x; 1.0930x over previous
//
#include <hip/hip_runtime.h>

#define D 128

// ---------------- MFMA frag types (per guide: short8 holds 8 bf16) --------
typedef __attribute__((ext_vector_type(8))) short bf16x8;
typedef __attribute__((ext_vector_type(4))) float f32x4;

union Frag {
    unsigned short s[8];
    uint4 u;
    bf16x8 v;
};

__device__ inline unsigned short bf16_rne(float x) {
    unsigned u = __float_as_uint(x);
    return (unsigned short)((u + 0x7fffu + ((u >> 16) & 1)) >> 16);
}

// ---------------- edge dtype handling ----------------
// Reference declares int64 edge_index, but JAX default (x64 disabled) yields
// int32. Detect on device: if the first 4096 odd 32-bit words are all zero,
// the buffer is little-endian int64 (values < 2^17).
__global__ void detect64_k(const int* __restrict__ raw, int* __restrict__ flag) {
    __shared__ int bad;
    if (threadIdx.x == 0) bad = 0;
    __syncthreads();
    for (int i = threadIdx.x; i < 4096; i += 256)
        if (raw[2 * i + 1] != 0) bad = 1;   // benign race, all write 1
    __syncthreads();
    if (threadIdx.x == 0) *flag = bad ? 0 : 1;
}

// ---------------- degree ----------------
__global__ void hist_k(const int* __restrict__ raw, const int* __restrict__ flag,
                       int* __restrict__ cnt, int E) {
    bool is64 = (*flag != 0);
    for (int i = blockIdx.x * blockDim.x + threadIdx.x; i < E;
         i += gridDim.x * blockDim.x) {
        int d = is64 ? raw[2 * (E + i)] : raw[E + i];
        atomicAdd(&cnt[d], 1);
    }
}

__global__ void dinv_k(const int* __restrict__ cnt, float* __restrict__ dinv, int n) {
    int i = blockIdx.x * blockDim.x + threadIdx.x;
    if (i < n) dinv[i] = rsqrtf((float)cnt[i] + 1.0f);   // +1 = self-loop
}

// ---------------- CSR build: block scan (1024 elems/block) ----------------
__global__ void scan1_k(const int* __restrict__ cnt, int* __restrict__ rp,
                        int* __restrict__ part, int n) {
    __shared__ int s[256];
    int t = threadIdx.x;
    int base = blockIdx.x * 1024 + t * 4;
    int v0 = 0, v1 = 0, v2 = 0, v3 = 0;
    if (base + 0 < n) v0 = cnt[base + 0];
    if (base + 1 < n) v1 = cnt[base + 1];
    if (base + 2 < n) v2 = cnt[base + 2];
    if (base + 3 < n) v3 = cnt[base + 3];
    int sum = v0 + v1 + v2 + v3;
    s[t] = sum;
    __syncthreads();
    for (int off = 1; off < 256; off <<= 1) {
        int xv = 0;
        if (t >= off) xv = s[t - off];
        __syncthreads();
        s[t] += xv;
        __syncthreads();
    }
    int run = s[t] - sum;   // exclusive prefix for this thread's 4 elems
    if (base + 0 < n) rp[base + 0] = run; run += v0;
    if (base + 1 < n) rp[base + 1] = run; run += v1;
    if (base + 2 < n) rp[base + 2] = run; run += v2;
    if (base + 3 < n) rp[base + 3] = run;
    if (t == 255) part[blockIdx.x] = s[255];
}

__global__ void scan2_k(int* __restrict__ part, int nb) {
    if (threadIdx.x == 0 && blockIdx.x == 0) {
        int run = 0;
        for (int i = 0; i < nb; i++) { int v = part[i]; part[i] = run; run += v; }
    }
}

__global__ void scan3_k(int* __restrict__ rp, int* __restrict__ cursor,
                        const int* __restrict__ part, int n, int E) {
    int i = blockIdx.x * blockDim.x + threadIdx.x;
    if (i < n) {
        int v = rp[i] + part[i >> 10];
        rp[i] = v;
        cursor[i] = v;
    }
    if (i == 0) rp[n] = E;
}

// CSR entry = {src index, norm weight dinv[src]*dinv[dst]} packed as int2
__global__ void build_k(const int* __restrict__ raw, const int* __restrict__ flag,
                        const float* __restrict__ dinv,
                        int* __restrict__ cursor, int2* __restrict__ csr, int E) {
    bool is64 = (*flag != 0);
    for (int i = blockIdx.x * blockDim.x + threadIdx.x; i < E;
         i += gridDim.x * blockDim.x) {
        int s = is64 ? raw[2 * i] : raw[i];
        int d = is64 ? raw[2 * (E + i)] : raw[E + i];
        int pos = atomicAdd(&cursor[d], 1);
        float w = dinv[s] * dinv[d];
        csr[pos] = make_int2(s, __float_as_int(w));
    }
}

// ---------------- W pre-split + frag-pack (once per call, per layer) -------
// f32 W[128][128] -> hi/lo bf16 frags stored in MFMA per-lane order:
// frag (s,t,lane): 8 bf16 at k = s*32 + (lane>>4)*8 + j, col = t*16 + (lane&15).
// gemm then reads frags as fully-coalesced 16 B/lane loads (L2-resident).
// The same k-bijection is used for the A frag, so any HW k-permutation
// uncertainty cancels (A and B agree); C/D layout is the m89-verified one.
__global__ void pack_k(const float* __restrict__ W, uint4* __restrict__ whi,
                       uint4* __restrict__ wlo) {
    int id = blockIdx.x * 256 + threadIdx.x;   // 2048 frag-lanes
    if (id >= 2048) return;
    int lane = id & 63, st = id >> 6;          // st = s*8 + t
    int s = st >> 3, t = st & 7;
    int col = t * 16 + (lane & 15);
    int kb = s * 32 + ((lane >> 4) & 3) * 8;
    Frag H, L;
#pragma unroll
    for (int j = 0; j < 8; ++j) {
        float x = W[(size_t)(kb + j) * D + col];
        unsigned u = __float_as_uint(x);
        unsigned r = (u + 0x7fffu + ((u >> 16) & 1)) & 0xffff0000u;
        H.s[j] = (unsigned short)(r >> 16);
        L.s[j] = bf16_rne(x - __uint_as_float(r));
    }
    whi[st * 64 + lane] = H.u;
    wlo[st * 64 + lane] = L.u;
}

// ---------------- GEMM: H = preop(A) @ W via split-bf16 MFMA ---------------
// f32 = bf16_hi + bf16_lo; D = Ah*Wh + Al*Wh + Ah*Wl (dropped Al*Wl <= 2^-18).
// 256 thr = 4 waves, each wave: 16 rows x 128 cols, K=128 in 4 MFMA k-steps.
// A read direct from global (each byte consumed once), W frags from L2.
template <int PRE>   // 0: identity, 1: relu on A-load
__global__ __launch_bounds__(256) void gemm_mfma_k(const float* __restrict__ A,
        const uint4* __restrict__ whi, const uint4* __restrict__ wlo,
        float* __restrict__ H, int M) {
    int wv = threadIdx.x >> 6, lane = threadIdx.x & 63;
    int row0 = blockIdx.x * 64 + wv * 16;
    int arow = row0 + (lane & 15);
    if (arow >= M) arow = M - 1;                       // clamp; stores guarded
    const float* ap = A + (size_t)arow * D + ((lane >> 4) & 3) * 8;
    f32x4 acc[8];
#pragma unroll
    for (int t = 0; t < 8; ++t) acc[t] = (f32x4){0.f, 0.f, 0.f, 0.f};
#pragma unroll
    for (int s = 0; s < 4; ++s) {
        float4 a0 = *(const float4*)(ap + s * 32);
        float4 a1 = *(const float4*)(ap + s * 32 + 4);
        float av[8] = {a0.x, a0.y, a0.z, a0.w, a1.x, a1.y, a1.z, a1.w};
        Frag Ah, Al;
#pragma unroll
        for (int j = 0; j < 8; ++j) {
            float x = av[j];
            if (PRE) x = fmaxf(x, 0.f);
            unsigned u = __float_as_uint(x);
            unsigned r = (u + 0x7fffu + ((u >> 16) & 1)) & 0xffff0000u;
            Ah.s[j] = (unsigned short)(r >> 16);
            Al.s[j] = bf16_rne(x - __uint_as_float(r));
        }
        const uint4* wh = whi + (size_t)s * 8 * 64 + lane;
        const uint4* wl = wlo + (size_t)s * 8 * 64 + lane;
#pragma unroll
        for (int t = 0; t < 8; ++t) {
            Frag Bh, Bl;
            Bh.u = wh[t * 64];
            Bl.u = wl[t * 64];
            acc[t] = __builtin_amdgcn_mfma_f32_16x16x32_bf16(Ah.v, Bh.v, acc[t], 0, 0, 0);
            acc[t] = __builtin_amdgcn_mfma_f32_16x16x32_bf16(Al.v, Bh.v, acc[t], 0, 0, 0);
            acc[t] = __builtin_amdgcn_mfma_f32_16x16x32_bf16(Ah.v, Bl.v, acc[t], 0, 0, 0);
        }
    }
    // C/D layout (m89-verified): col = lane&15, row = (lane>>4)*4 + reg
    int g = (lane >> 4) & 3, c = lane & 15;
#pragma unroll
    for (int r = 0; r < 4; ++r) {
        int row = row0 + g * 4 + r;
        if (row < M) {
#pragma unroll
            for (int t = 0; t < 8; ++t)
                H[(size_t)row * D + t * 16 + c] = acc[t][r];
        }
    }
}

// ---------------- CSR aggregation: out[n] = b + dinv[n]^2 h[n] + sum --------
// one wave per node; 64 lanes x float2 = 128 cols; 8-edge unroll for MLP
// (latency-bound: need more loads in flight), weights pre-folded in csr.
__global__ __launch_bounds__(256) void agg_k(const float* __restrict__ h,
                                             const float* __restrict__ dinv,
                                             const int* __restrict__ rp,
                                             const int2* __restrict__ csr,
                                             const float* __restrict__ bias,
                                             float* __restrict__ out, int n) {
    int node = (blockIdx.x << 2) + (threadIdx.x >> 6);
    int lane = threadIdx.x & 63;
    if (node >= n) return;
    const float2* h2 = (const float2*)h;
    float2 b2 = ((const float2*)bias)[lane];
    float dn = dinv[node];
    float2 hv = h2[(size_t)node * 64 + lane];
    float sl = dn * dn;   // self-loop norm
    float accx = b2.x + sl * hv.x;
    float accy = b2.y + sl * hv.y;
    int e = rp[node], e1 = rp[node + 1];
    for (; e + 8 <= e1; e += 8) {
        int2 p0 = csr[e + 0], p1 = csr[e + 1], p2 = csr[e + 2], p3 = csr[e + 3];
        int2 p4 = csr[e + 4], p5 = csr[e + 5], p6 = csr[e + 6], p7 = csr[e + 7];
        float2 v0 = h2[(size_t)p0.x * 64 + lane];
        float2 v1 = h2[(size_t)p1.x * 64 + lane];
        float2 v2 = h2[(size_t)p2.x * 64 + lane];
        float2 v3 = h2[(size_t)p3.x * 64 + lane];
        float2 v4 = h2[(size_t)p4.x * 64 + lane];
        float2 v5 = h2[(size_t)p5.x * 64 + lane];
        float2 v6 = h2[(size_t)p6.x * 64 + lane];
        float2 v7 = h2[(size_t)p7.x * 64 + lane];
        float w0 = __int_as_float(p0.y), w1 = __int_as_float(p1.y);
        float w2 = __int_as_float(p2.y), w3 = __int_as_float(p3.y);
        float w4 = __int_as_float(p4.y), w5 = __int_as_float(p5.y);
        float w6 = __int_as_float(p6.y), w7 = __int_as_float(p7.y);
        accx += w0 * v0.x + w1 * v1.x + w2 * v2.x + w3 * v3.x
              + w4 * v4.x + w5 * v5.x + w6 * v6.x + w7 * v7.x;
        accy += w0 * v0.y + w1 * v1.y + w2 * v2.y + w3 * v3.y
              + w4 * v4.y + w5 * v5.y + w6 * v6.y + w7 * v7.y;
    }
    for (; e + 4 <= e1; e += 4) {
        int2 p0 = csr[e + 0], p1 = csr[e + 1], p2 = csr[e + 2], p3 = csr[e + 3];
        float2 v0 = h2[(size_t)p0.x * 64 + lane];
        float2 v1 = h2[(size_t)p1.x * 64 + lane];
        float2 v2 = h2[(size_t)p2.x * 64 + lane];
        float2 v3 = h2[(size_t)p3.x * 64 + lane];
        float w0 = __int_as_float(p0.y), w1 = __int_as_float(p1.y);
        float w2 = __int_as_float(p2.y), w3 = __int_as_float(p3.y);
        accx += w0 * v0.x + w1 * v1.x + w2 * v2.x + w3 * v3.x;
        accy += w0 * v0.y + w1 * v1.y + w2 * v2.y + w3 * v3.y;
    }
    for (; e < e1; ++e) {
        int2 p0 = csr[e];
        float w0 = __int_as_float(p0.y);
        float2 v0 = h2[(size_t)p0.x * 64 + lane];
        accx += w0 * v0.x;
        accy += w0 * v0.y;
    }
    float2 o; o.x = accx; o.y = accy;
    ((float2*)out)[(size_t)node * 64 + lane] = o;
}

extern "C" void kernel_launch(void* const* d_in, const int* in_sizes, int n_in,
                              void* d_out, int out_size, void* d_ws, size_t ws_size,
                              hipStream_t stream) {
    const float* x  = (const float*)d_in[0];
    const int* eraw = (const int*)d_in[1];
    const float* W1 = (const float*)d_in[2];
    const float* b1 = (const float*)d_in[3];
    const float* W2 = (const float*)d_in[4];
    const float* b2 = (const float*)d_in[5];
    const float* W3 = (const float*)d_in[6];
    const float* b3 = (const float*)d_in[7];
    int N = in_sizes[0] / D;
    int E = in_sizes[1] / 2;
    float* out = (float*)d_out;

    // workspace carve-up (~66 MB)
    char* w = (char*)d_ws;
    float* h    = (float*)w; w += (size_t)N * D * 4;
    int2* csr   = (int2*)w;  w += (size_t)E * 8;
    int* cnt    = (int*)w;   w += (size_t)N * 4;
    float* dinv = (float*)w; w += (size_t)N * 4;
    int* rp     = (int*)w;   w += (size_t)(N + 1) * 4;
    int* cursor = (int*)w;   w += (size_t)N * 4;
    int* part   = (int*)w;   w += 1024 * 4;
    int* flag   = (int*)w;   w += 16;
    uint4* whi[3]; uint4* wlo[3];
    for (int l = 0; l < 3; ++l) {
        whi[l] = (uint4*)w; w += 2048 * 16;
        wlo[l] = (uint4*)w; w += 2048 * 16;
    }

    // graph structure (recomputed every call; inputs restored by harness)
    detect64_k<<<1, 256, 0, stream>>>(eraw, flag);
    hipMemsetAsync(cnt, 0, (size_t)N * 4, stream);
    hist_k<<<2048, 256, 0, stream>>>(eraw, flag, cnt, E);
    dinv_k<<<(N + 255) / 256, 256, 0, stream>>>(cnt, dinv, N);
    int nb = (N + 1023) / 1024;
    scan1_k<<<nb, 256, 0, stream>>>(cnt, rp, part, N);
    scan2_k<<<1, 64, 0, stream>>>(part, nb);
    scan3_k<<<(N + 255) / 256, 256, 0, stream>>>(rp, cursor, part, N, E);
    build_k<<<2048, 256, 0, stream>>>(eraw, flag, dinv, cursor, csr, E);

    // W frag pre-pack (hi/lo split, MFMA lane order)
    pack_k<<<8, 256, 0, stream>>>(W1, whi[0], wlo[0]);
    pack_k<<<8, 256, 0, stream>>>(W2, whi[1], wlo[1]);
    pack_k<<<8, 256, 0, stream>>>(W3, whi[2], wlo[2]);

    int gb = (N + 63) / 64;
    int ab = (N + 3) / 4;
    // layer 1
    gemm_mfma_k<0><<<gb, 256, 0, stream>>>(x, whi[0], wlo[0], h, N);
    agg_k<<<ab, 256, 0, stream>>>(h, dinv, rp, csr, b1, out, N);
    // layer 2 (relu fused into A-load)
    gemm_mfma_k<1><<<gb, 256, 0, stream>>>(out, whi[1], wlo[1], h, N);
    agg_k<<<ab, 256, 0, stream>>>(h, dinv, rp, csr, b2, out, N);
    // layer 3 (no relu after)
    gemm_mfma_k<1><<<gb, 256, 0, stream>>>(out, whi[2], wlo[2], h, N);
    agg_k<<<ab, 256, 0, stream>>>(h, dinv, rp, csr, b3, out, N);
}